// Round 1
// baseline (453.656 us; speedup 1.0000x reference)
//
#include <hip/hip_runtime.h>
#include <hip/hip_bf16.h>
#include <stdint.h>

typedef __bf16 bf16x8 __attribute__((ext_vector_type(8)));
typedef float f32x4 __attribute__((ext_vector_type(4)));
typedef unsigned short u16;
typedef u16 u16x4 __attribute__((ext_vector_type(4)));

#define S_LEN 2048
#define DMODEL 2048
#define NHEADS 32
#define BATCH 2
#define MROWS (BATCH * S_LEN)   // 4096
#define BIAS_LEN 1024

__device__ __forceinline__ u16 f2b(float f) {
  union { float f; uint32_t u; } v; v.f = f;
  return (u16)((v.u + 0x7FFFu + ((v.u >> 16) & 1u)) >> 16);
}

__device__ __forceinline__ void gload16(const void* g, void* l) {
  __builtin_amdgcn_global_load_lds(
      (const __attribute__((address_space(1))) uint32_t*)g,
      (__attribute__((address_space(3))) uint32_t*)l, 16, 0, 0);
}

// ---------------- f32 -> bf16 conversion ----------------
__global__ __launch_bounds__(256)
void cvt_bf16(const float* __restrict__ in, u16* __restrict__ out, int n) {
  int i = (blockIdx.x * 256 + threadIdx.x) * 4;
  if (i >= n) return;
  float4 v = *(const float4*)(in + i);
  u16x4 o = { f2b(v.x), f2b(v.y), f2b(v.z), f2b(v.w) };
  *(u16x4*)(out + i) = o;
}

// ---------------- RoPE cos/sin tables [S][32] ----------------
__global__ __launch_bounds__(256)
void rope_tab(float* __restrict__ ct, float* __restrict__ st) {
  int idx = blockIdx.x * 256 + threadIdx.x;
  if (idx >= S_LEN * 32) return;
  int s = idx >> 5, d = idx & 31;
  // inv_freq = 10000^(-d/32) = exp2(-d * log2(10000)/32)
  float inv = exp2f((float)d * (-13.287712379549449f / 32.0f));
  float a = (float)s * inv;
  ct[idx] = cosf(a);
  st[idx] = sinf(a);
}

// ---------------- GEMM: C = A(MxK) * B(NxK)^T, bf16 in, fused epilogues ----
// EPI 1: RoPE + 0.125 scale, store q [B,H,S,D] bf16
// EPI 2: RoPE, store k [B,H,S,D] bf16
// EPI 3: transpose-store v^T [B,H,D,S] bf16
// EPI 4: plain f32 store [M][N]
template<int EPI>
__global__ __launch_bounds__(256)
void gemm_bt(const u16* __restrict__ A, const u16* __restrict__ Bm,
             void* __restrict__ Cout,
             const float* __restrict__ ctab, const float* __restrict__ stab)
{
  __shared__ u16 sA[128 * 64];
  __shared__ u16 sB[128 * 64];
  const int tid  = threadIdx.x;
  const int lane = tid & 63;
  const int wid  = tid >> 6;
  const int wm   = wid >> 1, wn = wid & 1;
  const int lc   = lane & 15, lr = lane >> 4;
  const int tm   = blockIdx.y * 128;
  const int tn   = blockIdx.x * 128;

  f32x4 acc[4][4] = {};

  // staging sources, source-chunk pre-swizzled (XOR involution, rule #21)
  const u16* aS[4]; const u16* bS[4];
#pragma unroll
  for (int it = 0; it < 4; ++it) {
    int u = it * 256 + tid;
    int row = u >> 3;
    int ch  = (u & 7) ^ (row & 7);
    aS[it] = A  + (size_t)(tm + row) * DMODEL + ch * 8;
    bS[it] = Bm + (size_t)(tn + row) * DMODEL + ch * 8;
  }

  for (int k0 = 0; k0 < DMODEL; k0 += 64) {
    __syncthreads();
#pragma unroll
    for (int it = 0; it < 4; ++it) {
      int u = it * 256 + tid;
      gload16(aS[it] + k0, (char*)sA + u * 16);
      gload16(bS[it] + k0, (char*)sB + u * 16);
    }
    __syncthreads();
#pragma unroll
    for (int kk = 0; kk < 2; ++kk) {
      bf16x8 af[4], bq[4];
#pragma unroll
      for (int mi = 0; mi < 4; ++mi) {
        int row = wm * 64 + mi * 16 + lc;
        int ch  = (kk * 4 + lr) ^ (row & 7);
        af[mi] = *(const bf16x8*)((const char*)sA + row * 128 + ch * 16);
      }
#pragma unroll
      for (int ni = 0; ni < 4; ++ni) {
        int row = wn * 64 + ni * 16 + lc;
        int ch  = (kk * 4 + lr) ^ (row & 7);
        bq[ni] = *(const bf16x8*)((const char*)sB + row * 128 + ch * 16);
      }
#pragma unroll
      for (int mi = 0; mi < 4; ++mi)
#pragma unroll
        for (int ni = 0; ni < 4; ++ni)
          acc[mi][ni] = __builtin_amdgcn_mfma_f32_16x16x32_bf16(af[mi], bq[ni], acc[mi][ni], 0, 0, 0);
    }
  }

  // epilogue.  C/D layout: col = lane&15, row = (lane>>4)*4 + j  (HW-verified)
  if constexpr (EPI == 4) {
    float* C = (float*)Cout;
#pragma unroll
    for (int mi = 0; mi < 4; ++mi)
#pragma unroll
      for (int ni = 0; ni < 4; ++ni)
#pragma unroll
        for (int j = 0; j < 4; ++j) {
          int r = tm + wm * 64 + mi * 16 + lr * 4 + j;
          int c = tn + wn * 64 + ni * 16 + lc;
          C[(size_t)r * DMODEL + c] = acc[mi][ni][j];
        }
  } else if constexpr (EPI == 3) {
    u16* C = (u16*)Cout;   // v^T [B,H,D,S]
#pragma unroll
    for (int mi = 0; mi < 4; ++mi)
#pragma unroll
      for (int ni = 0; ni < 4; ++ni) {
        int col = tn + wn * 64 + ni * 16 + lc;
        int hh = col >> 6, d = col & 63;
        int m0 = tm + wm * 64 + mi * 16 + lr * 4;
        int bb = m0 >> 11, s = m0 & 2047;
        u16x4 v = { f2b(acc[mi][ni][0]), f2b(acc[mi][ni][1]),
                    f2b(acc[mi][ni][2]), f2b(acc[mi][ni][3]) };
        *(u16x4*)(C + (((size_t)bb * NHEADS + hh) * 64 + d) * S_LEN + s) = v;
      }
  } else {
    u16* C = (u16*)Cout;   // q/k [B,H,S,D], RoPE fused: pairs (d, d+32) = (ni, ni+2)
#pragma unroll
    for (int mi = 0; mi < 4; ++mi)
#pragma unroll
      for (int ni = 0; ni < 2; ++ni)
#pragma unroll
        for (int j = 0; j < 4; ++j) {
          int col = tn + wn * 64 + ni * 16 + lc;
          int hh = col >> 6, dl = col & 63;   // dl in [0,32)
          int r = tm + wm * 64 + mi * 16 + lr * 4 + j;
          int bb = r >> 11, s = r & 2047;
          float x1 = acc[mi][ni][j], x2 = acc[mi][ni + 2][j];
          float cv = ctab[s * 32 + dl], sv = stab[s * 32 + dl];
          float o1 = x1 * cv - x2 * sv;
          float o2 = x1 * sv + x2 * cv;
          if constexpr (EPI == 1) { o1 *= 0.125f; o2 *= 0.125f; }  // softmax scale folded into q
          size_t base = (((size_t)bb * NHEADS + hh) * S_LEN + s) * 64 + dl;
          C[base]      = f2b(o1);
          C[base + 32] = f2b(o2);
        }
  }
}

// ---------------- fused causal attention with banded bias ----------------
// grid (S/64, B*H), 4 waves; wave owns 16 q-rows; K/V tiles of 64 staged in LDS
__global__ __launch_bounds__(256)
void attn_kernel(const u16* __restrict__ Q, const u16* __restrict__ K,
                 const u16* __restrict__ V, const float* __restrict__ biasg,
                 const float* __restrict__ offg, u16* __restrict__ O)
{
  __shared__ u16 sK[64 * 64];
  __shared__ u16 sV[64 * 64];
  __shared__ u16 sP[4][16 * 80];    // per-wave P tile, padded rows (16B aligned)
  __shared__ float sBias[BIAS_LEN];

  const int tid = threadIdx.x, lane = tid & 63, wid = tid >> 6;
  const int lc = lane & 15, lr = lane >> 4;
  const int qt = blockIdx.x;
  const int bh = blockIdx.y;
  const int h  = bh & 31;
  const int b  = bh >> 5;
  const int qb = qt * 64;

  for (int i = tid; i < BIAS_LEN; i += 256) sBias[i] = biasg[h * BIAS_LEN + i];
  const float off = offg[h];

  // Q fragments from global (q already RoPE'd + 0.125-scaled)
  const u16* qp = Q + ((size_t)bh * S_LEN + qb + wid * 16 + lc) * 64;
  bf16x8 aq[2];
  aq[0] = *(const bf16x8*)(qp + lr * 8);
  aq[1] = *(const bf16x8*)(qp + 32 + lr * 8);

  const u16* kS[2]; const u16* vS[2];
#pragma unroll
  for (int it = 0; it < 2; ++it) {
    int u = it * 256 + tid;
    int row = u >> 3;
    int ch  = (u & 7) ^ (row & 7);
    kS[it] = K + ((size_t)bh * S_LEN + row) * 64 + ch * 8;
    vS[it] = V + ((size_t)bh * 64 + row) * S_LEN + ch * 8;
  }

  float m[4], lsum[4];
  f32x4 o[4] = {};
#pragma unroll
  for (int j = 0; j < 4; ++j) { m[j] = off; lsum[j] = 1.0f; }  // carries exp(off-m) term
  int irow[4];
#pragma unroll
  for (int j = 0; j < 4; ++j) irow[j] = qb + wid * 16 + lr * 4 + j;

  const int ntiles = qt + 1;
  for (int t = 0; t < ntiles; ++t) {
    const int kt = t * 64;
    __syncthreads();
#pragma unroll
    for (int it = 0; it < 2; ++it) {
      int u = it * 256 + tid;
      gload16(kS[it] + (size_t)kt * 64, (char*)sK + u * 16);
      gload16(vS[it] + kt,              (char*)sV + u * 16);
    }
    __syncthreads();

    // QK^T : 4 col-fragments x (D=64 -> 2 MFMAs)
    f32x4 sc[4];
#pragma unroll
    for (int f = 0; f < 4; ++f) {
      int row = f * 16 + lc;
      bf16x8 b0 = *(const bf16x8*)((const char*)sK + row * 128 + ((lr) ^ (row & 7)) * 16);
      bf16x8 b1 = *(const bf16x8*)((const char*)sK + row * 128 + ((4 + lr) ^ (row & 7)) * 16);
      f32x4 z = {};
      z     = __builtin_amdgcn_mfma_f32_16x16x32_bf16(aq[0], b0, z, 0, 0, 0);
      sc[f] = __builtin_amdgcn_mfma_f32_16x16x32_bf16(aq[1], b1, z, 0, 0, 0);
    }

    // bias + causal mask
    float pv[4][4];
    float pmax[4] = {-1e30f, -1e30f, -1e30f, -1e30f};
#pragma unroll
    for (int f = 0; f < 4; ++f) {
      int jg = kt + f * 16 + lc;
#pragma unroll
      for (int j = 0; j < 4; ++j) {
        int dd = irow[j] - jg;
        float bb = (dd >= 0 && dd < BIAS_LEN) ? sBias[dd] : 0.0f;
        float val = (dd >= 0) ? (sc[f][j] + bb) : -1e30f;
        pv[f][j] = val;
        pmax[j] = fmaxf(pmax[j], val);
      }
    }
#pragma unroll
    for (int d = 1; d < 16; d <<= 1)
#pragma unroll
      for (int j = 0; j < 4; ++j)
        pmax[j] = fmaxf(pmax[j], __shfl_xor(pmax[j], d, 64));

    float alpha[4], rsum[4];
#pragma unroll
    for (int j = 0; j < 4; ++j) {
      float mn = fmaxf(m[j], pmax[j]);
      alpha[j] = __expf(m[j] - mn);
      m[j] = mn;
      lsum[j] *= alpha[j];
      rsum[j] = 0.0f;
    }
#pragma unroll
    for (int f = 0; f < 4; ++f)
#pragma unroll
      for (int j = 0; j < 4; ++j) {
        float p = __expf(pv[f][j] - m[j]);
        pv[f][j] = p;
        rsum[j] += p;
      }
#pragma unroll
    for (int d = 1; d < 16; d <<= 1)
#pragma unroll
      for (int j = 0; j < 4; ++j)
        rsum[j] += __shfl_xor(rsum[j], d, 64);
#pragma unroll
    for (int j = 0; j < 4; ++j) lsum[j] += rsum[j];
#pragma unroll
    for (int f2 = 0; f2 < 4; ++f2)
#pragma unroll
      for (int j = 0; j < 4; ++j) o[f2][j] *= alpha[j];

    // P -> LDS (C-layout -> A-layout reshape), wave-local
    u16* myP = sP[wid];
#pragma unroll
    for (int f = 0; f < 4; ++f)
#pragma unroll
      for (int j = 0; j < 4; ++j)
        myP[(lr * 4 + j) * 80 + f * 16 + lc] = f2b(pv[f][j]);
    __threadfence_block();   // lgkmcnt(0): writes visible wave-wide

    // PV: O(16x64) += P(16x64) * V(64x64)
#pragma unroll
    for (int kk = 0; kk < 2; ++kk) {
      bf16x8 ap = *(const bf16x8*)(myP + lc * 80 + kk * 32 + lr * 8);
#pragma unroll
      for (int f2 = 0; f2 < 4; ++f2) {
        int drow = f2 * 16 + lc;
        int ch = (kk * 4 + lr) ^ (drow & 7);
        bf16x8 bv = *(const bf16x8*)((const char*)sV + drow * 128 + ch * 16);
        o[f2] = __builtin_amdgcn_mfma_f32_16x16x32_bf16(ap, bv, o[f2], 0, 0, 0);
      }
    }
  }

  // normalize + store [B,S,H,D] bf16
#pragma unroll
  for (int f2 = 0; f2 < 4; ++f2)
#pragma unroll
    for (int j = 0; j < 4; ++j) {
      int i = qb + wid * 16 + lr * 4 + j;
      int d = f2 * 16 + lc;
      size_t addr = (((size_t)(b * S_LEN + i)) * NHEADS + h) * 64 + d;
      O[addr] = f2b(o[f2][j] / lsum[j]);
    }
}

// ---------------- launcher ----------------
extern "C" void kernel_launch(void* const* d_in, const int* in_sizes, int n_in,
                              void* d_out, int out_size, void* d_ws, size_t ws_size,
                              hipStream_t stream)
{
  const float* hs   = (const float*)d_in[0];
  const float* Wq   = (const float*)d_in[1];
  const float* Wk   = (const float*)d_in[2];
  const float* Wv   = (const float*)d_in[3];
  const float* Wo   = (const float*)d_in[4];
  const float* bias = (const float*)d_in[5];
  const float* off  = (const float*)d_in[6];

  char* p = (char*)d_ws;
  u16* hs_b = (u16*)p; p += (size_t)MROWS * DMODEL * 2;
  u16* wq_b = (u16*)p; p += (size_t)DMODEL * DMODEL * 2;
  u16* wk_b = (u16*)p; p += (size_t)DMODEL * DMODEL * 2;
  u16* wv_b = (u16*)p; p += (size_t)DMODEL * DMODEL * 2;
  u16* wo_b = (u16*)p; p += (size_t)DMODEL * DMODEL * 2;
  u16* qf   = (u16*)p; p += (size_t)MROWS * DMODEL * 2;
  u16* kf   = (u16*)p; p += (size_t)MROWS * DMODEL * 2;
  u16* vt   = (u16*)p; p += (size_t)MROWS * DMODEL * 2;
  u16* att  = (u16*)p; p += (size_t)MROWS * DMODEL * 2;
  float* ct = (float*)p; p += (size_t)S_LEN * 32 * 4;
  float* st = (float*)p; p += (size_t)S_LEN * 32 * 4;
  (void)ws_size; (void)in_sizes; (void)n_in; (void)out_size;

  cvt_bf16<<<(MROWS * DMODEL) / 1024, 256, 0, stream>>>(hs, hs_b, MROWS * DMODEL);
  cvt_bf16<<<(DMODEL * DMODEL) / 1024, 256, 0, stream>>>(Wq, wq_b, DMODEL * DMODEL);
  cvt_bf16<<<(DMODEL * DMODEL) / 1024, 256, 0, stream>>>(Wk, wk_b, DMODEL * DMODEL);
  cvt_bf16<<<(DMODEL * DMODEL) / 1024, 256, 0, stream>>>(Wv, wv_b, DMODEL * DMODEL);
  cvt_bf16<<<(DMODEL * DMODEL) / 1024, 256, 0, stream>>>(Wo, wo_b, DMODEL * DMODEL);
  rope_tab<<<(S_LEN * 32) / 256, 256, 0, stream>>>(ct, st);

  dim3 g(DMODEL / 128, MROWS / 128);
  gemm_bt<1><<<g, 256, 0, stream>>>(hs_b, wq_b, qf, ct, st);
  gemm_bt<2><<<g, 256, 0, stream>>>(hs_b, wk_b, kf, ct, st);
  gemm_bt<3><<<g, 256, 0, stream>>>(hs_b, wv_b, vt, nullptr, nullptr);
  attn_kernel<<<dim3(S_LEN / 64, BATCH * NHEADS), 256, 0, stream>>>(qf, kf, vt, bias, off, att);
  gemm_bt<4><<<g, 256, 0, stream>>>(att, wo_b, d_out, nullptr, nullptr);
}

// Round 2
// 351.931 us; speedup vs baseline: 1.2890x; 1.2890x over previous
//
#include <hip/hip_runtime.h>
#include <hip/hip_bf16.h>
#include <stdint.h>

typedef __bf16 bf16x8 __attribute__((ext_vector_type(8)));
typedef float f32x4 __attribute__((ext_vector_type(4)));
typedef unsigned short u16;
typedef u16 u16x4 __attribute__((ext_vector_type(4)));

#define S_LEN 2048
#define DMODEL 2048
#define NHEADS 32
#define BATCH 2
#define MROWS (BATCH * S_LEN)   // 4096
#define BIAS_LEN 1024

__device__ __forceinline__ u16 f2b(float f) {
  union { float f; uint32_t u; } v; v.f = f;
  return (u16)((v.u + 0x7FFFu + ((v.u >> 16) & 1u)) >> 16);
}

__device__ __forceinline__ void gload16(const void* g, void* l) {
  __builtin_amdgcn_global_load_lds(
      (const __attribute__((address_space(1))) uint32_t*)g,
      (__attribute__((address_space(3))) uint32_t*)l, 16, 0, 0);
}

// ---------------- f32 -> bf16 conversion ----------------
__global__ __launch_bounds__(256)
void cvt_bf16(const float* __restrict__ in, u16* __restrict__ out, int n) {
  int i = (blockIdx.x * 256 + threadIdx.x) * 4;
  if (i >= n) return;
  float4 v = *(const float4*)(in + i);
  u16x4 o = { f2b(v.x), f2b(v.y), f2b(v.z), f2b(v.w) };
  *(u16x4*)(out + i) = o;
}

// ---------------- RoPE cos/sin tables [S][32] ----------------
__global__ __launch_bounds__(256)
void rope_tab(float* __restrict__ ct, float* __restrict__ st) {
  int idx = blockIdx.x * 256 + threadIdx.x;
  if (idx >= S_LEN * 32) return;
  int s = idx >> 5, d = idx & 31;
  float inv = exp2f((float)d * (-13.287712379549449f / 32.0f));
  float a = (float)s * inv;
  ct[idx] = cosf(a);
  st[idx] = sinf(a);
}

// ---------------- GEMM: C = A(MxK) * B(NxK)^T, bf16 in, fused epilogues ----
// EPI 1: RoPE + 0.125 scale, store q [B,H,S,D] bf16
// EPI 2: RoPE, store k [B,H,S,D] bf16
// EPI 3: transpose-store v^T [B,H,D,S] bf16
// EPI 4: plain f32 store [M][N]
template<int EPI>
__global__ __launch_bounds__(256)
void gemm_bt(const u16* __restrict__ A, const u16* __restrict__ Bm,
             void* __restrict__ Cout,
             const float* __restrict__ ctab, const float* __restrict__ stab)
{
  __shared__ u16 sA[128 * 64];
  __shared__ u16 sB[128 * 64];
  const int tid  = threadIdx.x;
  const int lane = tid & 63;
  const int wid  = tid >> 6;
  const int wm   = wid >> 1, wn = wid & 1;
  const int lc   = lane & 15, lr = lane >> 4;
  const int tm   = blockIdx.y * 128;
  const int tn   = blockIdx.x * 128;

  f32x4 acc[4][4] = {};

  const u16* aS[4]; const u16* bS[4];
#pragma unroll
  for (int it = 0; it < 4; ++it) {
    int u = it * 256 + tid;
    int row = u >> 3;
    int ch  = (u & 7) ^ (row & 7);
    aS[it] = A  + (size_t)(tm + row) * DMODEL + ch * 8;
    bS[it] = Bm + (size_t)(tn + row) * DMODEL + ch * 8;
  }

  for (int k0 = 0; k0 < DMODEL; k0 += 64) {
    __syncthreads();
#pragma unroll
    for (int it = 0; it < 4; ++it) {
      int u = it * 256 + tid;
      gload16(aS[it] + k0, (char*)sA + u * 16);
      gload16(bS[it] + k0, (char*)sB + u * 16);
    }
    __syncthreads();
#pragma unroll
    for (int kk = 0; kk < 2; ++kk) {
      bf16x8 af[4], bq[4];
#pragma unroll
      for (int mi = 0; mi < 4; ++mi) {
        int row = wm * 64 + mi * 16 + lc;
        int ch  = (kk * 4 + lr) ^ (row & 7);
        af[mi] = *(const bf16x8*)((const char*)sA + row * 128 + ch * 16);
      }
#pragma unroll
      for (int ni = 0; ni < 4; ++ni) {
        int row = wn * 64 + ni * 16 + lc;
        int ch  = (kk * 4 + lr) ^ (row & 7);
        bq[ni] = *(const bf16x8*)((const char*)sB + row * 128 + ch * 16);
      }
#pragma unroll
      for (int mi = 0; mi < 4; ++mi)
#pragma unroll
        for (int ni = 0; ni < 4; ++ni)
          acc[mi][ni] = __builtin_amdgcn_mfma_f32_16x16x32_bf16(af[mi], bq[ni], acc[mi][ni], 0, 0, 0);
    }
  }

  if constexpr (EPI == 4) {
    float* C = (float*)Cout;
#pragma unroll
    for (int mi = 0; mi < 4; ++mi)
#pragma unroll
      for (int ni = 0; ni < 4; ++ni)
#pragma unroll
        for (int j = 0; j < 4; ++j) {
          int r = tm + wm * 64 + mi * 16 + lr * 4 + j;
          int c = tn + wn * 64 + ni * 16 + lc;
          C[(size_t)r * DMODEL + c] = acc[mi][ni][j];
        }
  } else if constexpr (EPI == 3) {
    u16* C = (u16*)Cout;   // v^T [B,H,D,S]
#pragma unroll
    for (int mi = 0; mi < 4; ++mi)
#pragma unroll
      for (int ni = 0; ni < 4; ++ni) {
        int col = tn + wn * 64 + ni * 16 + lc;
        int hh = col >> 6, d = col & 63;
        int m0 = tm + wm * 64 + mi * 16 + lr * 4;
        int bb = m0 >> 11, s = m0 & 2047;
        u16x4 v = { f2b(acc[mi][ni][0]), f2b(acc[mi][ni][1]),
                    f2b(acc[mi][ni][2]), f2b(acc[mi][ni][3]) };
        *(u16x4*)(C + (((size_t)bb * NHEADS + hh) * 64 + d) * S_LEN + s) = v;
      }
  } else {
    u16* C = (u16*)Cout;   // q/k [B,H,S,D], RoPE fused
#pragma unroll
    for (int mi = 0; mi < 4; ++mi)
#pragma unroll
      for (int ni = 0; ni < 2; ++ni)
#pragma unroll
        for (int j = 0; j < 4; ++j) {
          int col = tn + wn * 64 + ni * 16 + lc;
          int hh = col >> 6, dl = col & 63;
          int r = tm + wm * 64 + mi * 16 + lr * 4 + j;
          int bb = r >> 11, s = r & 2047;
          float x1 = acc[mi][ni][j], x2 = acc[mi][ni + 2][j];
          float cv = ctab[s * 32 + dl], sv = stab[s * 32 + dl];
          float o1 = x1 * cv - x2 * sv;
          float o2 = x1 * sv + x2 * cv;
          if constexpr (EPI == 1) { o1 *= 0.125f; o2 *= 0.125f; }
          size_t base = (((size_t)bb * NHEADS + hh) * S_LEN + s) * 64 + dl;
          C[base]      = f2b(o1);
          C[base + 32] = f2b(o2);
        }
  }
}

// ---------------- fused causal attention with banded bias ----------------
// Balanced pairing + shared KV sweep:
//   grid (16, B*H), 512 threads (8 waves).
//   Block pi handles q-tiles qtA=31-pi (waves 0-3) and qtB=pi (waves 4-7).
//   qtB's KV range is a prefix of qtA's -> one shared double-buffered sweep.
//   Longest blocks (pi=0) dispatch first.
__global__ __launch_bounds__(512)
void attn_kernel(const u16* __restrict__ Q, const u16* __restrict__ K,
                 const u16* __restrict__ V, const float* __restrict__ biasg,
                 const float* __restrict__ offg, u16* __restrict__ O)
{
  __shared__ u16 sK[2][64 * 64];
  __shared__ u16 sV[2][64 * 64];
  __shared__ u16 sP[8][16 * 72];     // per-wave P tile, stride 72 (16B-aligned rows)
  __shared__ float sBias[BIAS_LEN];

  const int tid = threadIdx.x, lane = tid & 63, wid = tid >> 6;
  const int lc = lane & 15, lr = lane >> 4;
  const int pi = blockIdx.x;         // 0..15
  const int bh = blockIdx.y;
  const int h  = bh & 31;
  const int b  = bh >> 5;
  const int qtA  = 31 - pi;
  const int myQt = (wid < 4) ? qtA : pi;
  const int qb   = myQt * 64;

  for (int i = tid; i < BIAS_LEN; i += 512) sBias[i] = biasg[h * BIAS_LEN + i];
  const float off = offg[h];

  // Q fragments (q already RoPE'd + 0.125-scaled)
  const u16* qp = Q + ((size_t)bh * S_LEN + qb + (wid & 3) * 16 + lc) * 64;
  bf16x8 aq0 = *(const bf16x8*)(qp + lr * 8);
  bf16x8 aq1 = *(const bf16x8*)(qp + 32 + lr * 8);

  // staging source (per-thread, source pre-swizzled; LDS dest linear)
  const int srow = tid >> 3;
  const int sch  = (tid & 7) ^ (srow & 7);
  const u16* kSrc = K + ((size_t)bh * S_LEN + srow) * 64 + sch * 8;
  const u16* vSrc = V + ((size_t)bh * 64 + srow) * S_LEN + sch * 8;

  float m[4], lsum[4];
  f32x4 o[4] = {};
#pragma unroll
  for (int j = 0; j < 4; ++j) { m[j] = off; lsum[j] = 1.0f; }
  int irow[4];
#pragma unroll
  for (int j = 0; j < 4; ++j) irow[j] = qb + (wid & 3) * 16 + lr * 4 + j;

  // prologue: stage tile 0 into buf 0
  gload16(kSrc, (char*)sK[0] + tid * 16);
  gload16(vSrc, (char*)sV[0] + tid * 16);
  __syncthreads();

  for (int t = 0; t <= qtA; ++t) {
    const int cur = t & 1;
    // issue next-tile prefetch FIRST (latency hides under compute; the
    // implicit vmcnt(0) before the end-of-loop barrier picks it up)
    if (t < qtA) {
      gload16(kSrc + (size_t)(t + 1) * 64 * 64, (char*)sK[cur ^ 1] + tid * 16);
      gload16(vSrc + (t + 1) * 64,              (char*)sV[cur ^ 1] + tid * 16);
    }

    if (t <= myQt) {
      const int kt = t * 64;
      // QK^T : 4 col-fragments x (D=64 -> 2 MFMAs)
      f32x4 sc[4];
#pragma unroll
      for (int f = 0; f < 4; ++f) {
        int row = f * 16 + lc;
        bf16x8 b0 = *(const bf16x8*)((const char*)sK[cur] + row * 128 + ((lr) ^ (row & 7)) * 16);
        bf16x8 b1 = *(const bf16x8*)((const char*)sK[cur] + row * 128 + ((4 + lr) ^ (row & 7)) * 16);
        f32x4 z = {};
        z     = __builtin_amdgcn_mfma_f32_16x16x32_bf16(aq0, b0, z, 0, 0, 0);
        sc[f] = __builtin_amdgcn_mfma_f32_16x16x32_bf16(aq1, b1, sc[f] = z, 0, 0, 0);
      }

      // bias + causal mask
      float pv[4][4];
      float pmax[4] = {-1e30f, -1e30f, -1e30f, -1e30f};
#pragma unroll
      for (int f = 0; f < 4; ++f) {
        int jg = kt + f * 16 + lc;
#pragma unroll
        for (int j = 0; j < 4; ++j) {
          int dd = irow[j] - jg;
          float bb = (dd >= 0 && dd < BIAS_LEN) ? sBias[dd] : 0.0f;
          float val = (dd >= 0) ? (sc[f][j] + bb) : -1e30f;
          pv[f][j] = val;
          pmax[j] = fmaxf(pmax[j], val);
        }
      }
#pragma unroll
      for (int d = 1; d < 16; d <<= 1)
#pragma unroll
        for (int j = 0; j < 4; ++j)
          pmax[j] = fmaxf(pmax[j], __shfl_xor(pmax[j], d, 64));

      float alpha[4], rsum[4];
#pragma unroll
      for (int j = 0; j < 4; ++j) {
        float mn = fmaxf(m[j], pmax[j]);
        alpha[j] = __expf(m[j] - mn);
        m[j] = mn;
        lsum[j] *= alpha[j];
        rsum[j] = 0.0f;
      }
#pragma unroll
      for (int f = 0; f < 4; ++f)
#pragma unroll
        for (int j = 0; j < 4; ++j) {
          float p = __expf(pv[f][j] - m[j]);
          pv[f][j] = p;
          rsum[j] += p;
        }
#pragma unroll
      for (int d = 1; d < 16; d <<= 1)
#pragma unroll
        for (int j = 0; j < 4; ++j)
          rsum[j] += __shfl_xor(rsum[j], d, 64);
#pragma unroll
      for (int j = 0; j < 4; ++j) lsum[j] += rsum[j];
#pragma unroll
      for (int f2 = 0; f2 < 4; ++f2)
#pragma unroll
        for (int j = 0; j < 4; ++j) o[f2][j] *= alpha[j];

      // P -> LDS (C-layout -> A-layout reshape), wave-local
      u16* myP = sP[wid];
#pragma unroll
      for (int f = 0; f < 4; ++f)
#pragma unroll
        for (int j = 0; j < 4; ++j)
          myP[(lr * 4 + j) * 72 + f * 16 + lc] = f2b(pv[f][j]);
      __threadfence_block();

      // PV: O(16x64) += P(16x64) * V(64x64)
#pragma unroll
      for (int kk = 0; kk < 2; ++kk) {
        bf16x8 ap = *(const bf16x8*)(myP + lc * 72 + kk * 32 + lr * 8);
#pragma unroll
        for (int f2 = 0; f2 < 4; ++f2) {
          int drow = f2 * 16 + lc;
          int chh = (kk * 4 + lr) ^ (drow & 7);
          bf16x8 bv = *(const bf16x8*)((const char*)sV[cur] + drow * 128 + chh * 16);
          o[f2] = __builtin_amdgcn_mfma_f32_16x16x32_bf16(ap, bv, o[f2], 0, 0, 0);
        }
      }
    }
    __syncthreads();   // implicit vmcnt(0): prefetch landed; all waves done with cur
  }

  // normalize + store [B,S,H,D] bf16
#pragma unroll
  for (int f2 = 0; f2 < 4; ++f2)
#pragma unroll
    for (int j = 0; j < 4; ++j) {
      int i = qb + (wid & 3) * 16 + lr * 4 + j;
      int d = f2 * 16 + lc;
      size_t addr = (((size_t)(b * S_LEN + i)) * NHEADS + h) * 64 + d;
      O[addr] = f2b(o[f2][j] / lsum[j]);
    }
}

// ---------------- launcher ----------------
extern "C" void kernel_launch(void* const* d_in, const int* in_sizes, int n_in,
                              void* d_out, int out_size, void* d_ws, size_t ws_size,
                              hipStream_t stream)
{
  const float* hs   = (const float*)d_in[0];
  const float* Wq   = (const float*)d_in[1];
  const float* Wk   = (const float*)d_in[2];
  const float* Wv   = (const float*)d_in[3];
  const float* Wo   = (const float*)d_in[4];
  const float* bias = (const float*)d_in[5];
  const float* off  = (const float*)d_in[6];

  char* p = (char*)d_ws;
  u16* hs_b = (u16*)p; p += (size_t)MROWS * DMODEL * 2;
  u16* wq_b = (u16*)p; p += (size_t)DMODEL * DMODEL * 2;
  u16* wk_b = (u16*)p; p += (size_t)DMODEL * DMODEL * 2;
  u16* wv_b = (u16*)p; p += (size_t)DMODEL * DMODEL * 2;
  u16* wo_b = (u16*)p; p += (size_t)DMODEL * DMODEL * 2;
  u16* qf   = (u16*)p; p += (size_t)MROWS * DMODEL * 2;
  u16* kf   = (u16*)p; p += (size_t)MROWS * DMODEL * 2;
  u16* vt   = (u16*)p; p += (size_t)MROWS * DMODEL * 2;
  u16* att  = (u16*)p; p += (size_t)MROWS * DMODEL * 2;
  float* ct = (float*)p; p += (size_t)S_LEN * 32 * 4;
  float* st = (float*)p; p += (size_t)S_LEN * 32 * 4;
  (void)ws_size; (void)in_sizes; (void)n_in; (void)out_size;

  cvt_bf16<<<(MROWS * DMODEL) / 1024, 256, 0, stream>>>(hs, hs_b, MROWS * DMODEL);
  cvt_bf16<<<(DMODEL * DMODEL) / 1024, 256, 0, stream>>>(Wq, wq_b, DMODEL * DMODEL);
  cvt_bf16<<<(DMODEL * DMODEL) / 1024, 256, 0, stream>>>(Wk, wk_b, DMODEL * DMODEL);
  cvt_bf16<<<(DMODEL * DMODEL) / 1024, 256, 0, stream>>>(Wv, wv_b, DMODEL * DMODEL);
  cvt_bf16<<<(DMODEL * DMODEL) / 1024, 256, 0, stream>>>(Wo, wo_b, DMODEL * DMODEL);
  rope_tab<<<(S_LEN * 32) / 256, 256, 0, stream>>>(ct, st);

  dim3 g(DMODEL / 128, MROWS / 128);
  gemm_bt<1><<<g, 256, 0, stream>>>(hs_b, wq_b, qf, ct, st);
  gemm_bt<2><<<g, 256, 0, stream>>>(hs_b, wk_b, kf, ct, st);
  gemm_bt<3><<<g, 256, 0, stream>>>(hs_b, wv_b, vt, nullptr, nullptr);
  attn_kernel<<<dim3(16, BATCH * NHEADS), 512, 0, stream>>>(qf, kf, vt, bias, off, att);
  gemm_bt<4><<<g, 256, 0, stream>>>(att, wo_b, d_out, nullptr, nullptr);
}

// Round 3
// 301.639 us; speedup vs baseline: 1.5040x; 1.1667x over previous
//
#include <hip/hip_runtime.h>
#include <hip/hip_bf16.h>
#include <stdint.h>

typedef __bf16 bf16x8 __attribute__((ext_vector_type(8)));
typedef float f32x4 __attribute__((ext_vector_type(4)));
typedef unsigned short u16;
typedef u16 u16x4 __attribute__((ext_vector_type(4)));

#define S_LEN 2048
#define DMODEL 2048
#define NHEADS 32
#define BATCH 2
#define MROWS (BATCH * S_LEN)   // 4096
#define BIAS_LEN 1024

// native f32->bf16 (RNE); compiler pairs these into v_cvt_pk_bf16_f32
__device__ __forceinline__ u16 b16(float f) {
  union { __bf16 h; u16 u; } cv; cv.h = (__bf16)f; return cv.u;
}

__device__ __forceinline__ void gload16(const void* g, void* l) {
  __builtin_amdgcn_global_load_lds(
      (const __attribute__((address_space(1))) uint32_t*)g,
      (__attribute__((address_space(3))) uint32_t*)l, 16, 0, 0);
}

// ---------------- f32 -> bf16 conversion ----------------
__global__ __launch_bounds__(256)
void cvt_bf16(const float* __restrict__ in, u16* __restrict__ out, int n) {
  int i = (blockIdx.x * 256 + threadIdx.x) * 4;
  if (i >= n) return;
  float4 v = *(const float4*)(in + i);
  u16x4 o = { b16(v.x), b16(v.y), b16(v.z), b16(v.w) };
  *(u16x4*)(out + i) = o;
}

// ---------------- RoPE cos/sin tables [S][32] ----------------
__global__ __launch_bounds__(256)
void rope_tab(float* __restrict__ ct, float* __restrict__ st) {
  int idx = blockIdx.x * 256 + threadIdx.x;
  if (idx >= S_LEN * 32) return;
  int s = idx >> 5, d = idx & 31;
  float inv = exp2f((float)d * (-13.287712379549449f / 32.0f));
  float a = (float)s * inv;
  ct[idx] = cosf(a);
  st[idx] = sinf(a);
}

// ---------------- GEMM: C = A(MxK) * B(NxK)^T, bf16 in, fused epilogues ----
// EPI 1: RoPE + 0.125 scale, store q [B,H,S,D] bf16
// EPI 2: RoPE, store k [B,H,S,D] bf16
// EPI 3: transpose-store v^T [B,H,D,S] bf16
// EPI 4: plain f32 store [M][N]
template<int EPI>
__global__ __launch_bounds__(256)
void gemm_bt(const u16* __restrict__ A, const u16* __restrict__ Bm,
             void* __restrict__ Cout,
             const float* __restrict__ ctab, const float* __restrict__ stab)
{
  __shared__ u16 sA[128 * 64];
  __shared__ u16 sB[128 * 64];
  const int tid  = threadIdx.x;
  const int lane = tid & 63;
  const int wid  = tid >> 6;
  const int wm   = wid >> 1, wn = wid & 1;
  const int lc   = lane & 15, lr = lane >> 4;
  const int tm   = blockIdx.y * 128;
  const int tn   = blockIdx.x * 128;

  f32x4 acc[4][4] = {};

  const u16* aS[4]; const u16* bS[4];
#pragma unroll
  for (int it = 0; it < 4; ++it) {
    int u = it * 256 + tid;
    int row = u >> 3;
    int ch  = (u & 7) ^ (row & 7);
    aS[it] = A  + (size_t)(tm + row) * DMODEL + ch * 8;
    bS[it] = Bm + (size_t)(tn + row) * DMODEL + ch * 8;
  }

  for (int k0 = 0; k0 < DMODEL; k0 += 64) {
    __syncthreads();
#pragma unroll
    for (int it = 0; it < 4; ++it) {
      int u = it * 256 + tid;
      gload16(aS[it] + k0, (char*)sA + u * 16);
      gload16(bS[it] + k0, (char*)sB + u * 16);
    }
    __syncthreads();
#pragma unroll
    for (int kk = 0; kk < 2; ++kk) {
      bf16x8 af[4], bq[4];
#pragma unroll
      for (int mi = 0; mi < 4; ++mi) {
        int row = wm * 64 + mi * 16 + lc;
        int ch  = (kk * 4 + lr) ^ (row & 7);
        af[mi] = *(const bf16x8*)((const char*)sA + row * 128 + ch * 16);
      }
#pragma unroll
      for (int ni = 0; ni < 4; ++ni) {
        int row = wn * 64 + ni * 16 + lc;
        int ch  = (kk * 4 + lr) ^ (row & 7);
        bq[ni] = *(const bf16x8*)((const char*)sB + row * 128 + ch * 16);
      }
#pragma unroll
      for (int mi = 0; mi < 4; ++mi)
#pragma unroll
        for (int ni = 0; ni < 4; ++ni)
          acc[mi][ni] = __builtin_amdgcn_mfma_f32_16x16x32_bf16(af[mi], bq[ni], acc[mi][ni], 0, 0, 0);
    }
  }

  if constexpr (EPI == 4) {
    float* C = (float*)Cout;
#pragma unroll
    for (int mi = 0; mi < 4; ++mi)
#pragma unroll
      for (int ni = 0; ni < 4; ++ni)
#pragma unroll
        for (int j = 0; j < 4; ++j) {
          int r = tm + wm * 64 + mi * 16 + lr * 4 + j;
          int c = tn + wn * 64 + ni * 16 + lc;
          C[(size_t)r * DMODEL + c] = acc[mi][ni][j];
        }
  } else if constexpr (EPI == 3) {
    u16* C = (u16*)Cout;   // v^T [B,H,D,S]
#pragma unroll
    for (int mi = 0; mi < 4; ++mi)
#pragma unroll
      for (int ni = 0; ni < 4; ++ni) {
        int col = tn + wn * 64 + ni * 16 + lc;
        int hh = col >> 6, d = col & 63;
        int m0 = tm + wm * 64 + mi * 16 + lr * 4;
        int bb = m0 >> 11, s = m0 & 2047;
        u16x4 v = { b16(acc[mi][ni][0]), b16(acc[mi][ni][1]),
                    b16(acc[mi][ni][2]), b16(acc[mi][ni][3]) };
        *(u16x4*)(C + (((size_t)bb * NHEADS + hh) * 64 + d) * S_LEN + s) = v;
      }
  } else {
    u16* C = (u16*)Cout;   // q/k [B,H,S,D], RoPE fused
#pragma unroll
    for (int mi = 0; mi < 4; ++mi)
#pragma unroll
      for (int ni = 0; ni < 2; ++ni)
#pragma unroll
        for (int j = 0; j < 4; ++j) {
          int col = tn + wn * 64 + ni * 16 + lc;
          int hh = col >> 6, dl = col & 63;
          int r = tm + wm * 64 + mi * 16 + lr * 4 + j;
          int bb = r >> 11, s = r & 2047;
          float x1 = acc[mi][ni][j], x2 = acc[mi][ni + 2][j];
          float cv = ctab[s * 32 + dl], sv = stab[s * 32 + dl];
          float o1 = x1 * cv - x2 * sv;
          float o2 = x1 * sv + x2 * cv;
          if constexpr (EPI == 1) { o1 *= 0.125f; o2 *= 0.125f; }
          size_t base = (((size_t)bb * NHEADS + hh) * S_LEN + s) * 64 + dl;
          C[base]      = b16(o1);
          C[base + 32] = b16(o2);
        }
  }
}

// ---------------- fused causal attention with banded bias ----------------
// Balanced pairing + shared KV sweep (as before), but QK^T computed SWAPPED:
// S^T = K_tile x Q^T, so each lane holds 16 k-values of ONE q-row (q = qw+lc).
// Row reductions: in-register tree + 2 shallow shfl_xor. P is k-contiguous
// per lane -> packed b64 LDS writes. T13 defer-rescale with THR=8.
__global__ __launch_bounds__(512)
void attn_kernel(const u16* __restrict__ Q, const u16* __restrict__ K,
                 const u16* __restrict__ V, const float* __restrict__ biasg,
                 const float* __restrict__ offg, u16* __restrict__ O)
{
  __shared__ __align__(16) u16 sK[2][64 * 64];
  __shared__ __align__(16) u16 sV[2][64 * 64];
  __shared__ __align__(16) u16 sP[8][16 * 72];   // [q][k], stride 72
  __shared__ float sBias[BIAS_LEN];

  const int tid = threadIdx.x, lane = tid & 63, wid = tid >> 6;
  const int lc = lane & 15, lr = lane >> 4;
  const int pi = blockIdx.x;         // 0..15
  const int bh = blockIdx.y;
  const int h  = bh & 31;
  const int b  = bh >> 5;
  const int qtA  = 31 - pi;
  const int myQt = (wid < 4) ? qtA : pi;
  const int qw   = myQt * 64 + (wid & 3) * 16;   // wave's 16-row q base

  for (int i = tid; i < BIAS_LEN; i += 512) sBias[i] = biasg[h * BIAS_LEN + i];
  const float off = offg[h];

  // Q fragments (RoPE'd + 0.125-scaled). Used as MFMA B-operand (swapped).
  const u16* qp = Q + ((size_t)bh * S_LEN + qw + lc) * 64;
  bf16x8 aq0 = *(const bf16x8*)(qp + lr * 8);
  bf16x8 aq1 = *(const bf16x8*)(qp + 32 + lr * 8);

  const int srow = tid >> 3;
  const int sch  = (tid & 7) ^ (srow & 7);
  const u16* kSrc = K + ((size_t)bh * S_LEN + srow) * 64 + sch * 8;
  const u16* vSrc = V + ((size_t)bh * 64 + srow) * S_LEN + sch * 8;

  float m = off, lsum = 1.0f;        // per-lane scalars for q = qw + lc
  f32x4 o[4] = {};

  gload16(kSrc, (char*)sK[0] + tid * 16);
  gload16(vSrc, (char*)sV[0] + tid * 16);
  __syncthreads();

  for (int t = 0; t <= qtA; ++t) {
    const int cur = t & 1;
    if (t < qtA) {
      gload16(kSrc + (size_t)(t + 1) * 64 * 64, (char*)sK[cur ^ 1] + tid * 16);
      gload16(vSrc + (t + 1) * 64,              (char*)sV[cur ^ 1] + tid * 16);
    }

    if (t <= myQt) {
      const int kt = t * 64;
      // QK^T swapped: S^T[k][q] = K_rows x Q^T.  K rows are the A-operand.
      f32x4 sc[4];
#pragma unroll
      for (int f = 0; f < 4; ++f) {
        int row = f * 16 + lc;
        bf16x8 k0 = *(const bf16x8*)((const char*)sK[cur] + row * 128 + ((lr) ^ (row & 7)) * 16);
        bf16x8 k1 = *(const bf16x8*)((const char*)sK[cur] + row * 128 + ((4 + lr) ^ (row & 7)) * 16);
        f32x4 z = {};
        z     = __builtin_amdgcn_mfma_f32_16x16x32_bf16(k0, aq0, z, 0, 0, 0);
        sc[f] = __builtin_amdgcn_mfma_f32_16x16x32_bf16(k1, aq1, z, 0, 0, 0);
      }

      // lane's q = qw + lc;  k = kt + koff,  koff = f*16 + lr*4 + j
      const int db  = qw + lc - kt;
      const int dqt = qw - kt;          // wave-uniform, multiple of 16
      float pvv[4][4];
      if (t == myQt) {                  // diagonal: causal mask, always in-band
#pragma unroll
        for (int f = 0; f < 4; ++f)
#pragma unroll
          for (int j = 0; j < 4; ++j) {
            int dd = db - (f * 16 + lr * 4 + j);
            float bb = sBias[dd & 1023];
            pvv[f][j] = (dd >= 0) ? sc[f][j] + bb : -1e30f;
          }
      } else if (dqt <= 1008) {         // interior, fully in-band: bias only
#pragma unroll
        for (int f = 0; f < 4; ++f)
#pragma unroll
          for (int j = 0; j < 4; ++j)
            pvv[f][j] = sc[f][j] + sBias[db - (f * 16 + lr * 4 + j)];
      } else if (dqt < 1088) {          // band edge: clip check only
#pragma unroll
        for (int f = 0; f < 4; ++f)
#pragma unroll
          for (int j = 0; j < 4; ++j) {
            int dd = db - (f * 16 + lr * 4 + j);
            float bb = (dd < 1024) ? sBias[dd & 1023] : 0.0f;
            pvv[f][j] = sc[f][j] + bb;
          }
      } else {                          // beyond band: raw scores
#pragma unroll
        for (int f = 0; f < 4; ++f)
#pragma unroll
          for (int j = 0; j < 4; ++j)
            pvv[f][j] = sc[f][j];
      }

      // row max: in-register tree + 2 shallow cross-lane steps
      float pmax = -1e30f;
#pragma unroll
      for (int f = 0; f < 4; ++f) {
        float a = fmaxf(fmaxf(pvv[f][0], pvv[f][1]), fmaxf(pvv[f][2], pvv[f][3]));
        pmax = fmaxf(pmax, a);
      }
      pmax = fmaxf(pmax, __shfl_xor(pmax, 16, 64));
      pmax = fmaxf(pmax, __shfl_xor(pmax, 32, 64));

      // T13 defer-rescale: only rescale when max grew by > 8
      if (__any(pmax > m + 8.0f)) {
        float mn = fmaxf(m, pmax);
        float al = __expf(m - mn);
        m = mn;
        lsum *= al;
        float aj[4];
#pragma unroll
        for (int j = 0; j < 4; ++j) aj[j] = __shfl(al, lr * 4 + j, 64);
#pragma unroll
        for (int f2 = 0; f2 < 4; ++f2)
#pragma unroll
          for (int j = 0; j < 4; ++j) o[f2][j] *= aj[j];
      }

      // exp + row-sum
      float rsum = 0.0f;
#pragma unroll
      for (int f = 0; f < 4; ++f)
#pragma unroll
        for (int j = 0; j < 4; ++j) {
          float p = __expf(pvv[f][j] - m);
          pvv[f][j] = p;
          rsum += p;
        }
      rsum += __shfl_xor(rsum, 16, 64);
      rsum += __shfl_xor(rsum, 32, 64);
      lsum += rsum;

      // P -> LDS: lane's 4 j-values are k-adjacent -> one b64 write per f
      u16* myP = sP[wid];
#pragma unroll
      for (int f = 0; f < 4; ++f) {
        u16x4 w = { b16(pvv[f][0]), b16(pvv[f][1]), b16(pvv[f][2]), b16(pvv[f][3]) };
        *(u16x4*)(myP + lc * 72 + f * 16 + lr * 4) = w;
      }
      __threadfence_block();

      // PV: O(16 q x 64 d) += P(16 q x 64 k) * V^T-tile
#pragma unroll
      for (int kk = 0; kk < 2; ++kk) {
        bf16x8 ap = *(const bf16x8*)(myP + lc * 72 + kk * 32 + lr * 8);
#pragma unroll
        for (int f2 = 0; f2 < 4; ++f2) {
          int drow = f2 * 16 + lc;
          int chh = (kk * 4 + lr) ^ (drow & 7);
          bf16x8 bv = *(const bf16x8*)((const char*)sV[cur] + drow * 128 + chh * 16);
          o[f2] = __builtin_amdgcn_mfma_f32_16x16x32_bf16(ap, bv, o[f2], 0, 0, 0);
        }
      }
    }
    __syncthreads();
  }

  // normalize + store [B,S,H,D] bf16.  o rows are q = qw + lr*4 + j; lsum
  // lives in lane lc == lr*4+j -> gather.
  float ls[4];
#pragma unroll
  for (int j = 0; j < 4; ++j) ls[j] = __shfl(lsum, lr * 4 + j, 64);
#pragma unroll
  for (int f2 = 0; f2 < 4; ++f2)
#pragma unroll
    for (int j = 0; j < 4; ++j) {
      int i = qw + lr * 4 + j;
      int d = f2 * 16 + lc;
      size_t addr = (((size_t)(b * S_LEN + i)) * NHEADS + h) * 64 + d;
      O[addr] = b16(o[f2][j] / ls[j]);
    }
}

// ---------------- launcher ----------------
extern "C" void kernel_launch(void* const* d_in, const int* in_sizes, int n_in,
                              void* d_out, int out_size, void* d_ws, size_t ws_size,
                              hipStream_t stream)
{
  const float* hs   = (const float*)d_in[0];
  const float* Wq   = (const float*)d_in[1];
  const float* Wk   = (const float*)d_in[2];
  const float* Wv   = (const float*)d_in[3];
  const float* Wo   = (const float*)d_in[4];
  const float* bias = (const float*)d_in[5];
  const float* off  = (const float*)d_in[6];

  char* p = (char*)d_ws;
  u16* hs_b = (u16*)p; p += (size_t)MROWS * DMODEL * 2;
  u16* wq_b = (u16*)p; p += (size_t)DMODEL * DMODEL * 2;
  u16* wk_b = (u16*)p; p += (size_t)DMODEL * DMODEL * 2;
  u16* wv_b = (u16*)p; p += (size_t)DMODEL * DMODEL * 2;
  u16* wo_b = (u16*)p; p += (size_t)DMODEL * DMODEL * 2;
  u16* qf   = (u16*)p; p += (size_t)MROWS * DMODEL * 2;
  u16* kf   = (u16*)p; p += (size_t)MROWS * DMODEL * 2;
  u16* vt   = (u16*)p; p += (size_t)MROWS * DMODEL * 2;
  u16* att  = (u16*)p; p += (size_t)MROWS * DMODEL * 2;
  float* ct = (float*)p; p += (size_t)S_LEN * 32 * 4;
  float* st = (float*)p; p += (size_t)S_LEN * 32 * 4;
  (void)ws_size; (void)in_sizes; (void)n_in; (void)out_size;

  cvt_bf16<<<(MROWS * DMODEL) / 1024, 256, 0, stream>>>(hs, hs_b, MROWS * DMODEL);
  cvt_bf16<<<(DMODEL * DMODEL) / 1024, 256, 0, stream>>>(Wq, wq_b, DMODEL * DMODEL);
  cvt_bf16<<<(DMODEL * DMODEL) / 1024, 256, 0, stream>>>(Wk, wk_b, DMODEL * DMODEL);
  cvt_bf16<<<(DMODEL * DMODEL) / 1024, 256, 0, stream>>>(Wv, wv_b, DMODEL * DMODEL);
  cvt_bf16<<<(DMODEL * DMODEL) / 1024, 256, 0, stream>>>(Wo, wo_b, DMODEL * DMODEL);
  rope_tab<<<(S_LEN * 32) / 256, 256, 0, stream>>>(ct, st);

  dim3 g(DMODEL / 128, MROWS / 128);
  gemm_bt<1><<<g, 256, 0, stream>>>(hs_b, wq_b, qf, ct, st);
  gemm_bt<2><<<g, 256, 0, stream>>>(hs_b, wk_b, kf, ct, st);
  gemm_bt<3><<<g, 256, 0, stream>>>(hs_b, wv_b, vt, nullptr, nullptr);
  attn_kernel<<<dim3(16, BATCH * NHEADS), 512, 0, stream>>>(qf, kf, vt, bias, off, att);
  gemm_bt<4><<<g, 256, 0, stream>>>(att, wo_b, d_out, nullptr, nullptr);
}